// Round 2
// baseline (421.973 us; speedup 1.0000x reference)
//
#include <hip/hip_runtime.h>
#include <math.h>

#define Bv 2
#define Cc 4
#define Dd 64
#define Hh 192
#define Ww 192
#define HW (Hh*Ww)           // 36864
#define NSLICE (Bv*Dd)       // 128
#define NVOX ((size_t)NSLICE*HW)  // 4718592
#define DHW (Dd*HW)          // 2359296

typedef unsigned long long u64;

// masks layout: [slice][c-1][row][4] u64 (words 0..2 used, stride padded to 32B)
#define MROWSTRIDE 4
#define MASKU64 ((size_t)NSLICE*3*Hh*MROWSTRIDE)

// ---------------- Kernel A: pred byte, seed bitmasks (ballot), presence flags ----
// grid: NSLICE*Hh blocks of 192 threads; one pixel per thread, one row per block.
__global__ __launch_bounds__(192) void prep_kernel(const float* __restrict__ inp,
    const int* __restrict__ tgt, unsigned char* __restrict__ pred,
    u64* __restrict__ masks, unsigned int* __restrict__ flags) {
  int row   = blockIdx.x % Hh;
  int slice = blockIdx.x / Hh;
  int b = slice >> 6, d = slice & 63;
  int j = threadIdx.x;
  int idx = row*Ww + j;
  const float* base0 = inp + (size_t)(b*Cc)*DHW + (size_t)d*HW;
  const int*   tb    = tgt + (size_t)slice*HW;

  float x0 = base0[idx];
  float x1 = base0[DHW + idx];
  float x2 = base0[2*DHW + idx];
  float x3 = base0[3*DHW + idx];
  int p = 0; float best = x0;
  if (x1 > best) { best = x1; p = 1; }
  if (x2 > best) { best = x2; p = 2; }
  if (x3 > best) { best = x3; p = 3; }
  pred[(size_t)slice*HW + idx] = (unsigned char)p;

  int tv = tb[idx];
  int sc = 0;
  if (tv != 0) {
    bool interior = (row > 0) && (row < Hh-1) && (j > 0) && (j < Ww-1)
        && (tb[idx-Ww] == tv) && (tb[idx+Ww] == tv)
        && (tb[idx-1]  == tv) && (tb[idx+1]  == tv);
    if (!interior) sc = tv;   // boundary pixel of its own class
  }

  int wave = threadIdx.x >> 6;
  int lane = threadIdx.x & 63;
  #pragma unroll
  for (int c = 1; c <= 3; ++c) {
    u64 bal = __ballot(sc == c);
    if (lane == 0)
      masks[(((size_t)slice*3 + (c-1))*Hh + row)*MROWSTRIDE + wave] = bal;
  }

  __shared__ unsigned int sb;
  if (threadIdx.x == 0) sb = 0u;
  __syncthreads();
  if (tv != 0) atomicOr(&sb, 1u << (tv-1));
  __syncthreads();
  if (threadIdx.x == 0 && sb) atomicOr(&flags[slice], sb);
}

// nearest set bit distance from column j in a 192-bit row mask; 1<<20 if empty
__device__ __forceinline__ int nearest_bit_dist(u64 m0, u64 m1, u64 m2, int j) {
  int dr = 1<<20, dl = 1<<20;
  u64 r0, r1, r2;
  if (j >= 128)      { r0 = 0;  r1 = 0;  r2 = m2 & (~0ull << (j-128)); }
  else if (j >= 64)  { r0 = 0;  r1 = m1 & (~0ull << (j-64)); r2 = m2; }
  else               { r0 = m0 & (~0ull << j); r1 = m1; r2 = m2; }
  if      (r0) dr = (__ffsll((unsigned long long)r0) - 1) - j;
  else if (r1) dr = (__ffsll((unsigned long long)r1) + 63) - j;
  else if (r2) dr = (__ffsll((unsigned long long)r2) + 127) - j;
  u64 l0, l1, l2;
  if (j < 64)        { l0 = (j==63) ? m0 : (m0 & ((1ull<<(j+1))-1)); l1 = 0; l2 = 0; }
  else if (j < 128)  { l0 = m0; l1 = (j==127) ? m1 : (m1 & ((1ull<<(j-63))-1)); l2 = 0; }
  else               { l0 = m0; l1 = m1; l2 = (j==191) ? m2 : (m2 & ((1ull<<(j-127))-1)); }
  if      (l2) dl = j - (191 - __clzll((long long)l2));
  else if (l1) dl = j - (127 - __clzll((long long)l1));
  else if (l0) dl = j - (63  - __clzll((long long)l0));
  return dl < dr ? dl : dr;
}

// ---------------- Kernel B: exact EDT via ring search over row bitmasks ------
// grid: NSLICE*8 blocks of 256; each block: 24 rows of one slice.
// Also fuses the per-slice min/max reduction (uint atomics on nonneg floats).
__global__ __launch_bounds__(256) void edt_kernel(const int* __restrict__ tgt,
    const unsigned char* __restrict__ pred, const u64* __restrict__ masks,
    const unsigned int* __restrict__ flags, float* __restrict__ wmap,
    unsigned int* __restrict__ mnb, unsigned int* __restrict__ mxb) {
  int part  = blockIdx.x & 7;
  int slice = blockIdx.x >> 3;
  unsigned int fl = flags[slice];
  const u64* msl = masks + (size_t)slice*3*Hh*MROWSTRIDE;
  float lmn = 1.0e30f, lmx = 0.0f;
  for (int it = 0; it < (HW/8)/256; ++it) {
    int idx = part*(HW/8) + it*256 + threadIdx.x;
    int i = idx / Ww, j = idx - i*Ww;
    int tv = tgt[(size_t)slice*HW + idx];
    int pv = pred[(size_t)slice*HW + idx];
    float w = 0.0f;
    #pragma unroll
    for (int c = 1; c <= 3; ++c) {
      if (((tv == c) != (pv == c)) && ((fl >> (c-1)) & 1u)) {
        const u64* M = msl + (size_t)(c-1)*Hh*MROWSTRIDE;
        int best = 1 << 30;
        for (int dr = 0; dr < Hh; ++dr) {
          int dr2 = dr*dr;
          if (dr2 >= best) break;
          int up = i - dr;
          if (up >= 0) {
            const u64* R = M + up*MROWSTRIDE;
            int dc = nearest_bit_dist(R[0], R[1], R[2], j);
            if (dc < (1<<20)) { int cand = dr2 + dc*dc; if (cand < best) best = cand; }
          }
          int dn = i + dr;
          if (dr && dn < Hh) {
            const u64* R = M + dn*MROWSTRIDE;
            int dc = nearest_bit_dist(R[0], R[1], R[2], j);
            if (dc < (1<<20)) { int cand = dr2 + dc*dc; if (cand < best) best = cand; }
          }
        }
        w += (best == (1 << 30)) ? 1.0e6f : sqrtf((float)best);
      }
    }
    if (((fl & 7u) == 0u) && pv != 0) w += 10.0f;  // empty-slice penalty
    wmap[(size_t)slice*HW + idx] = w;
    lmn = fminf(lmn, w); lmx = fmaxf(lmx, w);
  }
  // block reduce min/max -> per-slice atomics (uint compare valid for nonneg floats)
  for (int off = 32; off; off >>= 1) {
    lmn = fminf(lmn, __shfl_xor(lmn, off));
    lmx = fmaxf(lmx, __shfl_xor(lmx, off));
  }
  __shared__ float smn[4], smx[4];
  int wid = threadIdx.x >> 6;
  if ((threadIdx.x & 63) == 0) { smn[wid] = lmn; smx[wid] = lmx; }
  __syncthreads();
  if (threadIdx.x == 0) {
    lmn = fminf(fminf(smn[0], smn[1]), fminf(smn[2], smn[3]));
    lmx = fmaxf(fmaxf(smx[0], smx[1]), fmaxf(smx[2], smx[3]));
    atomicMin(&mnb[slice], __float_as_uint(lmn));
    atomicMax(&mxb[slice], __float_as_uint(lmx));
  }
}

// ---------------- Kernel C: focal * exp(normalized wmap), reduce -------------
__global__ __launch_bounds__(256) void loss_kernel(const float* __restrict__ inp,
    const int* __restrict__ tgt, const float* __restrict__ wmap,
    const unsigned int* __restrict__ mnb, const unsigned int* __restrict__ mxb,
    float* __restrict__ out) {
  int part  = blockIdx.x & 7;
  int slice = blockIdx.x >> 3;
  int b = slice >> 6, d = slice & 63;
  const float* base0 = inp + (size_t)(b*Cc)*DHW + (size_t)d*HW + part*(HW/8);
  const int*   tb    = tgt + (size_t)slice*HW + part*(HW/8);
  const float* wb    = wmap + (size_t)slice*HW + part*(HW/8);
  float mn = __uint_as_float(mnb[slice]);
  float mx = __uint_as_float(mxb[slice]);
  float inv = 1.0f/(mx - mn + 1e-6f);
  float acc = 0.0f;
  for (int it = 0; it < (HW/8)/256; ++it) {
    int idx = it*256 + threadIdx.x;
    float x0 = base0[idx], x1 = base0[DHW+idx], x2 = base0[2*DHW+idx], x3 = base0[3*DHW+idx];
    int tv = tb[idx];
    float m = fmaxf(fmaxf(x0,x1), fmaxf(x2,x3));
    float e = expf(x0-m)+expf(x1-m)+expf(x2-m)+expf(x3-m);
    float xt = (tv==0) ? x0 : (tv==1) ? x1 : (tv==2) ? x2 : x3;
    float logpt = xt - m - logf(e);
    float pt = expf(logpt);
    float weight = expf((wb[idx]-mn)*inv);
    float omp = 1.0f - pt;
    acc += -(omp*omp)*logpt*weight;
  }
  for (int off = 32; off; off >>= 1) acc += __shfl_xor(acc, off);
  __shared__ float sa[4];
  int wid = threadIdx.x >> 6;
  if ((threadIdx.x & 63) == 0) sa[wid] = acc;
  __syncthreads();
  if (threadIdx.x == 0) atomicAdd(out, sa[0]+sa[1]+sa[2]+sa[3]);
}

extern "C" void kernel_launch(void* const* d_in, const int* in_sizes, int n_in,
                              void* d_out, int out_size, void* d_ws, size_t ws_size,
                              hipStream_t stream) {
  const float* inp = (const float*)d_in[0];
  const int*   tgt = (const int*)d_in[1];
  char* ws = (char*)d_ws;
  unsigned char* pred = (unsigned char*)ws;                 // NVOX bytes
  float*         wmap = (float*)(ws + NVOX);                // 4*NVOX bytes
  u64*          masks = (u64*)(ws + 5*NVOX);                // MASKU64*8 bytes
  unsigned int* flags = (unsigned int*)(ws + 5*NVOX + MASKU64*8); // NSLICE u32
  unsigned int* mxb   = flags + NSLICE;                     // NSLICE u32
  unsigned int* mnb   = mxb + NSLICE;                       // NSLICE u32

  hipMemsetAsync(flags, 0, NSLICE*2*sizeof(unsigned int), stream); // flags + mxb
  hipMemsetAsync(mnb, 0xFF, NSLICE*sizeof(unsigned int), stream);  // mnb = huge
  hipMemsetAsync(d_out, 0, sizeof(float), stream);

  prep_kernel<<<NSLICE*Hh, 192, 0, stream>>>(inp, tgt, pred, masks, flags);
  edt_kernel<<<NSLICE*8, 256, 0, stream>>>(tgt, pred, masks, flags, wmap, mnb, mxb);
  loss_kernel<<<NSLICE*8, 256, 0, stream>>>(inp, tgt, wmap, mnb, mxb, (float*)d_out);
}

// Round 3
// 314.821 us; speedup vs baseline: 1.3404x; 1.3404x over previous
//
#include <hip/hip_runtime.h>
#include <math.h>

#define Bv 2
#define Cc 4
#define Dd 64
#define Hh 192
#define Ww 192
#define HW (Hh*Ww)           // 36864
#define NSLICE (Bv*Dd)       // 128
#define NVOX ((size_t)NSLICE*HW)  // 4718592
#define DHW (Dd*HW)          // 2359296

typedef unsigned long long u64;

// masks layout: [slice][c-1][row][4] u64 (words 0..2 used, stride padded to 32B)
#define MROWSTRIDE 4
#define MASKU64 ((size_t)NSLICE*3*Hh*MROWSTRIDE)

// ---------------- Kernel A: focal + packed tv/pred + seed bitmasks + flags ----
// grid: NSLICE*8 blocks of 256. Each wave handles 6 rows; lanes 0..47 cover one
// row via float4/int4 (4 px/lane, 16B/lane loads). Seed masks packed with a
// 16-lane shfl-OR tree (pixel j=4*lane+k -> word lane>>4, bit 4*(lane&15)+k).
__global__ __launch_bounds__(256) void prep_kernel(const float* __restrict__ inp,
    const int* __restrict__ tgt, unsigned char* __restrict__ tp,
    float* __restrict__ focal, u64* __restrict__ masks,
    unsigned int* __restrict__ flags) {
  int part  = blockIdx.x & 7;
  int slice = blockIdx.x >> 3;
  int b = slice >> 6, d = slice & 63;
  int wave = threadIdx.x >> 6, lane = threadIdx.x & 63;
  const float* c0 = inp + ((size_t)(b*Cc)*Dd + d)*HW;
  const float* c1 = c0 + DHW;
  const float* c2 = c0 + 2*DHW;
  const float* c3 = c0 + 3*DHW;
  const int*   tb = tgt + (size_t)slice*HW;
  unsigned int lbits = 0;

  for (int it = 0; it < 6; ++it) {
    int row = part*24 + wave*6 + it;
    int idx = row*Ww + lane*4;
    float4 x0, x1, x2, x3;
    int4 tv4 = make_int4(0,0,0,0), up4 = make_int4(-1,-1,-1,-1), dn4 = make_int4(-1,-1,-1,-1);
    if (lane < 48) {
      x0 = *(const float4*)(c0 + idx);
      x1 = *(const float4*)(c1 + idx);
      x2 = *(const float4*)(c2 + idx);
      x3 = *(const float4*)(c3 + idx);
      tv4 = *(const int4*)(tb + idx);
      if (row > 0)    up4 = *(const int4*)(tb + idx - Ww);
      if (row < Hh-1) dn4 = *(const int4*)(tb + idx + Ww);
    }
    int lf = __shfl(tv4.w, (lane-1)&63);   // left of k=0 (garbage at col 0, guarded)
    int rt = __shfl(tv4.x, (lane+1)&63);   // right of k=3 (garbage at col 191, guarded)
    unsigned nib1 = 0, nib2 = 0, nib3 = 0;
    if (lane < 48) {
      int tvs[4] = {tv4.x, tv4.y, tv4.z, tv4.w};
      int ups[4] = {up4.x, up4.y, up4.z, up4.w};
      int dns[4] = {dn4.x, dn4.y, dn4.z, dn4.w};
      int lfs[4] = {lf, tv4.x, tv4.y, tv4.z};
      int rts[4] = {tv4.y, tv4.z, tv4.w, rt};
      float a0[4] = {x0.x, x0.y, x0.z, x0.w};
      float a1[4] = {x1.x, x1.y, x1.z, x1.w};
      float a2[4] = {x2.x, x2.y, x2.z, x2.w};
      float a3[4] = {x3.x, x3.y, x3.z, x3.w};
      float4 fout;
      float* fo = (float*)&fout;
      unsigned pk4 = 0;
      #pragma unroll
      for (int k = 0; k < 4; ++k) {
        float xa = a0[k], xb = a1[k], xc = a2[k], xd = a3[k];
        int p = 0; float bst = xa;
        if (xb > bst) { bst = xb; p = 1; }
        if (xc > bst) { bst = xc; p = 2; }
        if (xd > bst) { bst = xd; p = 3; }
        int tv = tvs[k];
        float m = fmaxf(fmaxf(xa, xb), fmaxf(xc, xd));
        float e = expf(xa-m) + expf(xb-m) + expf(xc-m) + expf(xd-m);
        float xt = (tv==0) ? xa : (tv==1) ? xb : (tv==2) ? xc : xd;
        float logpt = xt - m - logf(e);
        float pt = expf(logpt);
        float om = 1.0f - pt;
        fo[k] = -(om*om)*logpt;
        pk4 |= (unsigned)(tv | (p << 4)) << (8*k);
        if (tv != 0) {
          lbits |= 1u << (tv-1);
          int col = lane*4 + k;
          bool interior = (row > 0) && (row < Hh-1) && (col > 0) && (col < Ww-1)
              && (ups[k]==tv) && (dns[k]==tv) && (lfs[k]==tv) && (rts[k]==tv);
          if (!interior) {
            if      (tv == 1) nib1 |= 1u << k;
            else if (tv == 2) nib2 |= 1u << k;
            else              nib3 |= 1u << k;
          }
        }
      }
      *(float4*)(focal + (size_t)slice*HW + idx) = fout;
      *(unsigned*)(tp + (size_t)slice*HW + idx) = pk4;
    }
    u64 m1 = (u64)nib1 << ((lane & 15)*4);
    u64 m2 = (u64)nib2 << ((lane & 15)*4);
    u64 m3 = (u64)nib3 << ((lane & 15)*4);
    #pragma unroll
    for (int off = 1; off < 16; off <<= 1) {
      m1 |= __shfl_xor(m1, off);
      m2 |= __shfl_xor(m2, off);
      m3 |= __shfl_xor(m3, off);
    }
    if (lane < 48 && (lane & 15) == 0) {
      int word = lane >> 4;
      size_t base = ((size_t)slice*3*Hh + row)*MROWSTRIDE + word;
      masks[base]                    = m1;
      masks[base + Hh*MROWSTRIDE]    = m2;
      masks[base + 2*Hh*MROWSTRIDE]  = m3;
    }
  }
  __shared__ unsigned int sb;
  if (threadIdx.x == 0) sb = 0u;
  __syncthreads();
  if (lbits) atomicOr(&sb, lbits);
  __syncthreads();
  if (threadIdx.x == 0 && sb) atomicOr(&flags[slice], sb);
}

// nearest set bit distance from column j in a 192-bit row mask; 1<<20 if empty
__device__ __forceinline__ int nearest_bit_dist(u64 m0, u64 m1, u64 m2, int j) {
  int dr = 1<<20, dl = 1<<20;
  u64 r0, r1, r2;
  if (j >= 128)      { r0 = 0;  r1 = 0;  r2 = m2 & (~0ull << (j-128)); }
  else if (j >= 64)  { r0 = 0;  r1 = m1 & (~0ull << (j-64)); r2 = m2; }
  else               { r0 = m0 & (~0ull << j); r1 = m1; r2 = m2; }
  if      (r0) dr = (__ffsll((unsigned long long)r0) - 1) - j;
  else if (r1) dr = (__ffsll((unsigned long long)r1) + 63) - j;
  else if (r2) dr = (__ffsll((unsigned long long)r2) + 127) - j;
  u64 l0, l1, l2;
  if (j < 64)        { l0 = (j==63) ? m0 : (m0 & ((1ull<<(j+1))-1)); l1 = 0; l2 = 0; }
  else if (j < 128)  { l0 = m0; l1 = (j==127) ? m1 : (m1 & ((1ull<<(j-63))-1)); l2 = 0; }
  else               { l0 = m0; l1 = m1; l2 = (j==191) ? m2 : (m2 & ((1ull<<(j-127))-1)); }
  if      (l2) dl = j - (191 - __clzll((long long)l2));
  else if (l1) dl = j - (127 - __clzll((long long)l1));
  else if (l0) dl = j - (63  - __clzll((long long)l0));
  return dl < dr ? dl : dr;
}

// ---------------- Kernel B: exact EDT via ring search over row bitmasks ------
// grid: NSLICE*9 blocks of 256; 4096 px/block, uchar4 per thread-iter.
__global__ __launch_bounds__(256) void edt_kernel(const unsigned char* __restrict__ tp,
    const u64* __restrict__ masks, const unsigned int* __restrict__ flags,
    float* __restrict__ wmap, unsigned int* __restrict__ mnb,
    unsigned int* __restrict__ mxb) {
  int part  = blockIdx.x % 9;
  int slice = blockIdx.x / 9;
  unsigned int fl = flags[slice];
  const u64* msl = masks + (size_t)slice*3*Hh*MROWSTRIDE;
  float lmn = 1.0e30f, lmx = 0.0f;
  for (int it = 0; it < 4; ++it) {
    int idx = part*4096 + it*1024 + threadIdx.x*4;
    unsigned pk = *(const unsigned*)(tp + (size_t)slice*HW + idx);
    int i = idx / Ww;
    int j0 = idx - i*Ww;
    float4 wv;
    float* wp = (float*)&wv;
    #pragma unroll
    for (int k = 0; k < 4; ++k) {
      int byte = (pk >> (8*k)) & 0xff;
      int tv = byte & 15, pv = byte >> 4;
      int j = j0 + k;
      float w = 0.0f;
      #pragma unroll
      for (int c = 1; c <= 3; ++c) {
        if (((tv == c) != (pv == c)) && ((fl >> (c-1)) & 1u)) {
          const u64* M = msl + (size_t)(c-1)*Hh*MROWSTRIDE;
          int best = 1 << 30;
          for (int dr = 0; dr < Hh; ++dr) {
            int dr2 = dr*dr;
            if (dr2 >= best) break;
            int up = i - dr;
            if (up >= 0) {
              const u64* R = M + up*MROWSTRIDE;
              int dc = nearest_bit_dist(R[0], R[1], R[2], j);
              if (dc < (1<<20)) { int cand = dr2 + dc*dc; if (cand < best) best = cand; }
            }
            int dn = i + dr;
            if (dr && dn < Hh) {
              const u64* R = M + dn*MROWSTRIDE;
              int dc = nearest_bit_dist(R[0], R[1], R[2], j);
              if (dc < (1<<20)) { int cand = dr2 + dc*dc; if (cand < best) best = cand; }
            }
          }
          w += (best == (1 << 30)) ? 1.0e6f : sqrtf((float)best);
        }
      }
      if (((fl & 7u) == 0u) && pv != 0) w += 10.0f;
      wp[k] = w;
      lmn = fminf(lmn, w); lmx = fmaxf(lmx, w);
    }
    *(float4*)(wmap + (size_t)slice*HW + idx) = wv;
  }
  for (int off = 32; off; off >>= 1) {
    lmn = fminf(lmn, __shfl_xor(lmn, off));
    lmx = fmaxf(lmx, __shfl_xor(lmx, off));
  }
  __shared__ float smn[4], smx[4];
  int wid = threadIdx.x >> 6;
  if ((threadIdx.x & 63) == 0) { smn[wid] = lmn; smx[wid] = lmx; }
  __syncthreads();
  if (threadIdx.x == 0) {
    lmn = fminf(fminf(smn[0], smn[1]), fminf(smn[2], smn[3]));
    lmx = fmaxf(fmaxf(smx[0], smx[1]), fmaxf(smx[2], smx[3]));
    atomicMin(&mnb[slice], __float_as_uint(lmn));
    atomicMax(&mxb[slice], __float_as_uint(lmx));
  }
}

// ---------------- Kernel C: sum focal * exp(normalized wmap) -----------------
__global__ __launch_bounds__(256) void loss_kernel(const float* __restrict__ focal,
    const float* __restrict__ wmap, const unsigned int* __restrict__ mnb,
    const unsigned int* __restrict__ mxb, float* __restrict__ out) {
  int part  = blockIdx.x % 9;
  int slice = blockIdx.x / 9;
  float mn = __uint_as_float(mnb[slice]);
  float mx = __uint_as_float(mxb[slice]);
  float inv = 1.0f/(mx - mn + 1e-6f);
  float acc = 0.0f;
  for (int it = 0; it < 4; ++it) {
    int idx = part*4096 + it*1024 + threadIdx.x*4;
    float4 f = *(const float4*)(focal + (size_t)slice*HW + idx);
    float4 w = *(const float4*)(wmap + (size_t)slice*HW + idx);
    acc += f.x * expf((w.x-mn)*inv);
    acc += f.y * expf((w.y-mn)*inv);
    acc += f.z * expf((w.z-mn)*inv);
    acc += f.w * expf((w.w-mn)*inv);
  }
  for (int off = 32; off; off >>= 1) acc += __shfl_xor(acc, off);
  __shared__ float sa[4];
  int wid = threadIdx.x >> 6;
  if ((threadIdx.x & 63) == 0) sa[wid] = acc;
  __syncthreads();
  if (threadIdx.x == 0) atomicAdd(out, sa[0]+sa[1]+sa[2]+sa[3]);
}

extern "C" void kernel_launch(void* const* d_in, const int* in_sizes, int n_in,
                              void* d_out, int out_size, void* d_ws, size_t ws_size,
                              hipStream_t stream) {
  const float* inp = (const float*)d_in[0];
  const int*   tgt = (const int*)d_in[1];
  char* ws = (char*)d_ws;
  unsigned char* tp    = (unsigned char*)ws;                // NVOX bytes
  float*         focal = (float*)(ws + NVOX);               // 4*NVOX
  float*         wmap  = (float*)(ws + 5*NVOX);             // 4*NVOX
  u64*           masks = (u64*)(ws + 9*NVOX);               // MASKU64*8
  unsigned int*  flags = (unsigned int*)(ws + 9*NVOX + MASKU64*8);
  unsigned int*  mxb   = flags + NSLICE;
  unsigned int*  mnb   = mxb + NSLICE;

  hipMemsetAsync(flags, 0, NSLICE*2*sizeof(unsigned int), stream); // flags + mxb
  hipMemsetAsync(mnb, 0xFF, NSLICE*sizeof(unsigned int), stream);  // mnb = huge
  hipMemsetAsync(d_out, 0, sizeof(float), stream);

  prep_kernel<<<NSLICE*8, 256, 0, stream>>>(inp, tgt, tp, focal, masks, flags);
  edt_kernel<<<NSLICE*9, 256, 0, stream>>>(tp, masks, flags, wmap, mnb, mxb);
  loss_kernel<<<NSLICE*9, 256, 0, stream>>>(focal, wmap, mnb, mxb, (float*)d_out);
}

// Round 4
// 260.124 us; speedup vs baseline: 1.6222x; 1.2103x over previous
//
#include <hip/hip_runtime.h>
#include <math.h>

#define Bv 2
#define Cc 4
#define Dd 64
#define Hh 192
#define Ww 192
#define HW (Hh*Ww)           // 36864
#define NSLICE (Bv*Dd)       // 128
#define NVOX ((size_t)NSLICE*HW)  // 4718592
#define DHW (Dd*HW)          // 2359296

typedef unsigned long long u64;

// masks layout: [slice][c-1][row][4] u64 (words 0..2 used, stride padded to 32B)
#define MROWSTRIDE 4
#define MASKU64 ((size_t)NSLICE*3*Hh*MROWSTRIDE)

// ---------------- Kernel A: focal + packed tv/pred + seed bitmasks + flags ----
__global__ __launch_bounds__(256) void prep_kernel(const float* __restrict__ inp,
    const int* __restrict__ tgt, unsigned char* __restrict__ tp,
    float* __restrict__ focal, u64* __restrict__ masks,
    unsigned int* __restrict__ flags) {
  int part  = blockIdx.x & 7;
  int slice = blockIdx.x >> 3;
  int b = slice >> 6, d = slice & 63;
  int wave = threadIdx.x >> 6, lane = threadIdx.x & 63;
  const float* c0 = inp + ((size_t)(b*Cc)*Dd + d)*HW;
  const float* c1 = c0 + DHW;
  const float* c2 = c0 + 2*DHW;
  const float* c3 = c0 + 3*DHW;
  const int*   tb = tgt + (size_t)slice*HW;
  unsigned int lbits = 0;

  for (int it = 0; it < 6; ++it) {
    int row = part*24 + wave*6 + it;
    int idx = row*Ww + lane*4;
    float4 x0, x1, x2, x3;
    int4 tv4 = make_int4(0,0,0,0), up4 = make_int4(-1,-1,-1,-1), dn4 = make_int4(-1,-1,-1,-1);
    if (lane < 48) {
      x0 = *(const float4*)(c0 + idx);
      x1 = *(const float4*)(c1 + idx);
      x2 = *(const float4*)(c2 + idx);
      x3 = *(const float4*)(c3 + idx);
      tv4 = *(const int4*)(tb + idx);
      if (row > 0)    up4 = *(const int4*)(tb + idx - Ww);
      if (row < Hh-1) dn4 = *(const int4*)(tb + idx + Ww);
    }
    int lf = __shfl(tv4.w, (lane-1)&63);
    int rt = __shfl(tv4.x, (lane+1)&63);
    unsigned nib1 = 0, nib2 = 0, nib3 = 0;
    if (lane < 48) {
      int tvs[4] = {tv4.x, tv4.y, tv4.z, tv4.w};
      int ups[4] = {up4.x, up4.y, up4.z, up4.w};
      int dns[4] = {dn4.x, dn4.y, dn4.z, dn4.w};
      int lfs[4] = {lf, tv4.x, tv4.y, tv4.z};
      int rts[4] = {tv4.y, tv4.z, tv4.w, rt};
      float a0[4] = {x0.x, x0.y, x0.z, x0.w};
      float a1[4] = {x1.x, x1.y, x1.z, x1.w};
      float a2[4] = {x2.x, x2.y, x2.z, x2.w};
      float a3[4] = {x3.x, x3.y, x3.z, x3.w};
      float4 fout;
      float* fo = (float*)&fout;
      unsigned pk4 = 0;
      #pragma unroll
      for (int k = 0; k < 4; ++k) {
        float xa = a0[k], xb = a1[k], xc = a2[k], xd = a3[k];
        int p = 0; float bst = xa;
        if (xb > bst) { bst = xb; p = 1; }
        if (xc > bst) { bst = xc; p = 2; }
        if (xd > bst) { bst = xd; p = 3; }
        int tv = tvs[k];
        float m = fmaxf(fmaxf(xa, xb), fmaxf(xc, xd));
        float e = expf(xa-m) + expf(xb-m) + expf(xc-m) + expf(xd-m);
        float xt = (tv==0) ? xa : (tv==1) ? xb : (tv==2) ? xc : xd;
        float logpt = xt - m - logf(e);
        float pt = expf(logpt);
        float om = 1.0f - pt;
        fo[k] = -(om*om)*logpt;
        pk4 |= (unsigned)(tv | (p << 4)) << (8*k);
        if (tv != 0) {
          lbits |= 1u << (tv-1);
          int col = lane*4 + k;
          bool interior = (row > 0) && (row < Hh-1) && (col > 0) && (col < Ww-1)
              && (ups[k]==tv) && (dns[k]==tv) && (lfs[k]==tv) && (rts[k]==tv);
          if (!interior) {
            if      (tv == 1) nib1 |= 1u << k;
            else if (tv == 2) nib2 |= 1u << k;
            else              nib3 |= 1u << k;
          }
        }
      }
      *(float4*)(focal + (size_t)slice*HW + idx) = fout;
      *(unsigned*)(tp + (size_t)slice*HW + idx) = pk4;
    }
    u64 m1 = (u64)nib1 << ((lane & 15)*4);
    u64 m2 = (u64)nib2 << ((lane & 15)*4);
    u64 m3 = (u64)nib3 << ((lane & 15)*4);
    #pragma unroll
    for (int off = 1; off < 16; off <<= 1) {
      m1 |= __shfl_xor(m1, off);
      m2 |= __shfl_xor(m2, off);
      m3 |= __shfl_xor(m3, off);
    }
    if (lane < 48 && (lane & 15) == 0) {
      int word = lane >> 4;
      size_t base = ((size_t)slice*3*Hh + row)*MROWSTRIDE + word;
      masks[base]                    = m1;
      masks[base + Hh*MROWSTRIDE]    = m2;
      masks[base + 2*Hh*MROWSTRIDE]  = m3;
    }
  }
  __shared__ unsigned int sb;
  if (threadIdx.x == 0) sb = 0u;
  __syncthreads();
  if (lbits) atomicOr(&sb, lbits);
  __syncthreads();
  if (threadIdx.x == 0 && sb) atomicOr(&flags[slice], sb);
}

// nearest set bit distance from column j in a 192-bit row mask; 1<<20 if empty
__device__ __forceinline__ int nearest_bit_dist(u64 m0, u64 m1, u64 m2, int j) {
  int dr = 1<<20, dl = 1<<20;
  u64 r0, r1, r2;
  if (j >= 128)      { r0 = 0;  r1 = 0;  r2 = m2 & (~0ull << (j-128)); }
  else if (j >= 64)  { r0 = 0;  r1 = m1 & (~0ull << (j-64)); r2 = m2; }
  else               { r0 = m0 & (~0ull << j); r1 = m1; r2 = m2; }
  if      (r0) dr = (__ffsll((unsigned long long)r0) - 1) - j;
  else if (r1) dr = (__ffsll((unsigned long long)r1) + 63) - j;
  else if (r2) dr = (__ffsll((unsigned long long)r2) + 127) - j;
  u64 l0, l1, l2;
  if (j < 64)        { l0 = (j==63) ? m0 : (m0 & ((1ull<<(j+1))-1)); l1 = 0; l2 = 0; }
  else if (j < 128)  { l0 = m0; l1 = (j==127) ? m1 : (m1 & ((1ull<<(j-63))-1)); l2 = 0; }
  else               { l0 = m0; l1 = m1; l2 = (j==191) ? m2 : (m2 & ((1ull<<(j-127))-1)); }
  if      (l2) dl = j - (191 - __clzll((long long)l2));
  else if (l1) dl = j - (127 - __clzll((long long)l1));
  else if (l0) dl = j - (63  - __clzll((long long)l0));
  return dl < dr ? dl : dr;
}

// wave-aggregated worklist push: 1 LDS atomic per wave instead of per lane
__device__ __forceinline__ void push_items(volatile unsigned short* list,
    unsigned int* cnt, bool want, unsigned val) {
  u64 mask = __ballot(want);
  if (mask == 0) return;
  int lane = threadIdx.x & 63;
  int total = __popcll(mask);
  int leader = __ffsll((long long)mask) - 1;
  unsigned b = 0;
  if (lane == leader) b = atomicAdd(cnt, (unsigned)total);
  b = __shfl(b, leader);
  if (want) {
    int off = __popcll(mask & ((1ull << lane) - 1));
    list[b + off] = (unsigned short)val;
  }
}

// ---------------- Kernel B: worklist-compacted exact EDT ---------------------
// grid: NSLICE*9 blocks of 256; 4096 px per block.
// Phase 1: build (pixel,class) worklist in LDS (<=2 items/px), init wacc.
// Phase 2: all lanes uniformly process worklist items (ring search on bitmasks).
// Phase 3: writeback wmap + fused per-slice min/max.
__global__ __launch_bounds__(256) void edt_kernel(const unsigned char* __restrict__ tp,
    const u64* __restrict__ masks, const unsigned int* __restrict__ flags,
    float* __restrict__ wmap, unsigned int* __restrict__ mnb,
    unsigned int* __restrict__ mxb) {
  __shared__ __align__(16) float wacc[4096];
  __shared__ unsigned short list[8192];
  __shared__ unsigned int cnt;
  __shared__ float smn[4], smx[4];
  int part  = blockIdx.x % 9;
  int slice = blockIdx.x / 9;
  unsigned int fl = flags[slice];
  bool empty = ((fl & 7u) == 0u);
  if (threadIdx.x == 0) cnt = 0u;
  __syncthreads();

  // phase 1: worklist build + wacc init
  for (int it = 0; it < 4; ++it) {
    int lbase = it*1024 + threadIdx.x*4;
    unsigned pk = *(const unsigned*)(tp + (size_t)slice*HW + part*4096 + lbase);
    #pragma unroll
    for (int k = 0; k < 4; ++k) {
      int byte = (pk >> (8*k)) & 0xff;
      int tv = byte & 15, pv = byte >> 4;
      wacc[lbase+k] = (empty && pv != 0) ? 10.0f : 0.0f;
      bool diff = (tv != pv);
      bool w1 = diff && (tv >= 1) && ((fl >> (tv-1)) & 1u);
      bool w2 = diff && (pv >= 1) && ((fl >> (pv-1)) & 1u);
      push_items(list, &cnt, w1, (unsigned)(lbase+k) | ((unsigned)tv << 12));
      push_items(list, &cnt, w2, (unsigned)(lbase+k) | ((unsigned)pv << 12));
    }
  }
  __syncthreads();

  // phase 2: uniform ring searches
  unsigned n = cnt;
  const u64* msl = masks + (size_t)slice*3*Hh*MROWSTRIDE;
  for (unsigned kk = threadIdx.x; kk < n; kk += 256) {
    unsigned item = list[kk];
    int lidx = item & 4095;
    int c = item >> 12;
    int idx = part*4096 + lidx;
    int i = idx / Ww, j = idx - i*Ww;
    const u64* M = msl + (size_t)(c-1)*Hh*MROWSTRIDE;
    int best = 1 << 30;
    for (int dr = 0; dr < Hh; ++dr) {
      int dr2 = dr*dr;
      if (dr2 >= best) break;
      int up = i - dr;
      if (up >= 0) {
        const u64* R = M + up*MROWSTRIDE;
        int dc = nearest_bit_dist(R[0], R[1], R[2], j);
        if (dc < (1<<20)) { int cand = dr2 + dc*dc; if (cand < best) best = cand; }
      }
      int dn = i + dr;
      if (dr && dn < Hh) {
        const u64* R = M + dn*MROWSTRIDE;
        int dc = nearest_bit_dist(R[0], R[1], R[2], j);
        if (dc < (1<<20)) { int cand = dr2 + dc*dc; if (cand < best) best = cand; }
      }
    }
    float dist = (best == (1 << 30)) ? 1.0e6f : sqrtf((float)best);
    atomicAdd(&wacc[lidx], dist);
  }
  __syncthreads();

  // phase 3: writeback + min/max
  float lmn = 1.0e30f, lmx = 0.0f;
  for (int it = 0; it < 4; ++it) {
    int lbase = it*1024 + threadIdx.x*4;
    float4 wv = *(const float4*)&wacc[lbase];
    lmn = fminf(lmn, fminf(fminf(wv.x, wv.y), fminf(wv.z, wv.w)));
    lmx = fmaxf(lmx, fmaxf(fmaxf(wv.x, wv.y), fmaxf(wv.z, wv.w)));
    *(float4*)(wmap + (size_t)slice*HW + part*4096 + lbase) = wv;
  }
  for (int off = 32; off; off >>= 1) {
    lmn = fminf(lmn, __shfl_xor(lmn, off));
    lmx = fmaxf(lmx, __shfl_xor(lmx, off));
  }
  int wid = threadIdx.x >> 6;
  if ((threadIdx.x & 63) == 0) { smn[wid] = lmn; smx[wid] = lmx; }
  __syncthreads();
  if (threadIdx.x == 0) {
    lmn = fminf(fminf(smn[0], smn[1]), fminf(smn[2], smn[3]));
    lmx = fmaxf(fmaxf(smx[0], smx[1]), fmaxf(smx[2], smx[3]));
    atomicMin(&mnb[slice], __float_as_uint(lmn));
    atomicMax(&mxb[slice], __float_as_uint(lmx));
  }
}

// ---------------- Kernel C: sum focal * exp(normalized wmap) -----------------
__global__ __launch_bounds__(256) void loss_kernel(const float* __restrict__ focal,
    const float* __restrict__ wmap, const unsigned int* __restrict__ mnb,
    const unsigned int* __restrict__ mxb, float* __restrict__ out) {
  int part  = blockIdx.x % 9;
  int slice = blockIdx.x / 9;
  float mn = __uint_as_float(mnb[slice]);
  float mx = __uint_as_float(mxb[slice]);
  float inv = 1.0f/(mx - mn + 1e-6f);
  float acc = 0.0f;
  for (int it = 0; it < 4; ++it) {
    int idx = part*4096 + it*1024 + threadIdx.x*4;
    float4 f = *(const float4*)(focal + (size_t)slice*HW + idx);
    float4 w = *(const float4*)(wmap + (size_t)slice*HW + idx);
    acc += f.x * expf((w.x-mn)*inv);
    acc += f.y * expf((w.y-mn)*inv);
    acc += f.z * expf((w.z-mn)*inv);
    acc += f.w * expf((w.w-mn)*inv);
  }
  for (int off = 32; off; off >>= 1) acc += __shfl_xor(acc, off);
  __shared__ float sa[4];
  int wid = threadIdx.x >> 6;
  if ((threadIdx.x & 63) == 0) sa[wid] = acc;
  __syncthreads();
  if (threadIdx.x == 0) atomicAdd(out, sa[0]+sa[1]+sa[2]+sa[3]);
}

extern "C" void kernel_launch(void* const* d_in, const int* in_sizes, int n_in,
                              void* d_out, int out_size, void* d_ws, size_t ws_size,
                              hipStream_t stream) {
  const float* inp = (const float*)d_in[0];
  const int*   tgt = (const int*)d_in[1];
  char* ws = (char*)d_ws;
  unsigned char* tp    = (unsigned char*)ws;                // NVOX bytes
  float*         focal = (float*)(ws + NVOX);               // 4*NVOX
  float*         wmap  = (float*)(ws + 5*NVOX);             // 4*NVOX
  u64*           masks = (u64*)(ws + 9*NVOX);               // MASKU64*8
  unsigned int*  flags = (unsigned int*)(ws + 9*NVOX + MASKU64*8);
  unsigned int*  mxb   = flags + NSLICE;
  unsigned int*  mnb   = mxb + NSLICE;

  hipMemsetAsync(flags, 0, NSLICE*2*sizeof(unsigned int), stream); // flags + mxb
  hipMemsetAsync(mnb, 0xFF, NSLICE*sizeof(unsigned int), stream);  // mnb = huge
  hipMemsetAsync(d_out, 0, sizeof(float), stream);

  prep_kernel<<<NSLICE*8, 256, 0, stream>>>(inp, tgt, tp, focal, masks, flags);
  edt_kernel<<<NSLICE*9, 256, 0, stream>>>(tp, masks, flags, wmap, mnb, mxb);
  loss_kernel<<<NSLICE*9, 256, 0, stream>>>(focal, wmap, mnb, mxb, (float*)d_out);
}

// Round 5
// 230.392 us; speedup vs baseline: 1.8315x; 1.1290x over previous
//
#include <hip/hip_runtime.h>
#include <math.h>

#define Bv 2
#define Cc 4
#define Dd 64
#define Hh 192
#define Ww 192
#define HW (Hh*Ww)           // 36864
#define NSLICE (Bv*Dd)       // 128
#define NVOX ((size_t)NSLICE*HW)  // 4718592
#define DHW (Dd*HW)          // 2359296

typedef unsigned long long u64;

// masks layout: [slice][c-1][row][4] u64 (words 0..2 used, stride padded to 32B)
#define MROWSTRIDE 4
#define MASKU64 ((size_t)NSLICE*3*Hh*MROWSTRIDE)

// ---------------- Kernel A: focal + packed tv/pred + seed bitmasks + flags ----
__global__ __launch_bounds__(256) void prep_kernel(const float* __restrict__ inp,
    const int* __restrict__ tgt, unsigned char* __restrict__ tp,
    float* __restrict__ focal, u64* __restrict__ masks,
    unsigned int* __restrict__ flags) {
  int part  = blockIdx.x & 7;
  int slice = blockIdx.x >> 3;
  int b = slice >> 6, d = slice & 63;
  int wave = threadIdx.x >> 6, lane = threadIdx.x & 63;
  const float* c0 = inp + ((size_t)(b*Cc)*Dd + d)*HW;
  const float* c1 = c0 + DHW;
  const float* c2 = c0 + 2*DHW;
  const float* c3 = c0 + 3*DHW;
  const int*   tb = tgt + (size_t)slice*HW;
  unsigned int lbits = 0;

  for (int it = 0; it < 6; ++it) {
    int row = part*24 + wave*6 + it;
    int idx = row*Ww + lane*4;
    float4 x0, x1, x2, x3;
    int4 tv4 = make_int4(0,0,0,0), up4 = make_int4(-1,-1,-1,-1), dn4 = make_int4(-1,-1,-1,-1);
    if (lane < 48) {
      x0 = *(const float4*)(c0 + idx);
      x1 = *(const float4*)(c1 + idx);
      x2 = *(const float4*)(c2 + idx);
      x3 = *(const float4*)(c3 + idx);
      tv4 = *(const int4*)(tb + idx);
      if (row > 0)    up4 = *(const int4*)(tb + idx - Ww);
      if (row < Hh-1) dn4 = *(const int4*)(tb + idx + Ww);
    }
    int lf = __shfl(tv4.w, (lane-1)&63);
    int rt = __shfl(tv4.x, (lane+1)&63);
    unsigned nib1 = 0, nib2 = 0, nib3 = 0;
    if (lane < 48) {
      int tvs[4] = {tv4.x, tv4.y, tv4.z, tv4.w};
      int ups[4] = {up4.x, up4.y, up4.z, up4.w};
      int dns[4] = {dn4.x, dn4.y, dn4.z, dn4.w};
      int lfs[4] = {lf, tv4.x, tv4.y, tv4.z};
      int rts[4] = {tv4.y, tv4.z, tv4.w, rt};
      float a0[4] = {x0.x, x0.y, x0.z, x0.w};
      float a1[4] = {x1.x, x1.y, x1.z, x1.w};
      float a2[4] = {x2.x, x2.y, x2.z, x2.w};
      float a3[4] = {x3.x, x3.y, x3.z, x3.w};
      float4 fout;
      float* fo = (float*)&fout;
      unsigned pk4 = 0;
      #pragma unroll
      for (int k = 0; k < 4; ++k) {
        float xa = a0[k], xb = a1[k], xc = a2[k], xd = a3[k];
        int p = 0; float bst = xa;
        if (xb > bst) { bst = xb; p = 1; }
        if (xc > bst) { bst = xc; p = 2; }
        if (xd > bst) { bst = xd; p = 3; }
        int tv = tvs[k];
        float m = fmaxf(fmaxf(xa, xb), fmaxf(xc, xd));
        float e = expf(xa-m) + expf(xb-m) + expf(xc-m) + expf(xd-m);
        float xt = (tv==0) ? xa : (tv==1) ? xb : (tv==2) ? xc : xd;
        float logpt = xt - m - logf(e);
        float pt = expf(logpt);
        float om = 1.0f - pt;
        fo[k] = -(om*om)*logpt;
        pk4 |= (unsigned)(tv | (p << 4)) << (8*k);
        if (tv != 0) {
          lbits |= 1u << (tv-1);
          int col = lane*4 + k;
          bool interior = (row > 0) && (row < Hh-1) && (col > 0) && (col < Ww-1)
              && (ups[k]==tv) && (dns[k]==tv) && (lfs[k]==tv) && (rts[k]==tv);
          if (!interior) {
            if      (tv == 1) nib1 |= 1u << k;
            else if (tv == 2) nib2 |= 1u << k;
            else              nib3 |= 1u << k;
          }
        }
      }
      *(float4*)(focal + (size_t)slice*HW + idx) = fout;
      *(unsigned*)(tp + (size_t)slice*HW + idx) = pk4;
    }
    u64 m1 = (u64)nib1 << ((lane & 15)*4);
    u64 m2 = (u64)nib2 << ((lane & 15)*4);
    u64 m3 = (u64)nib3 << ((lane & 15)*4);
    #pragma unroll
    for (int off = 1; off < 16; off <<= 1) {
      m1 |= __shfl_xor(m1, off);
      m2 |= __shfl_xor(m2, off);
      m3 |= __shfl_xor(m3, off);
    }
    if (lane < 48 && (lane & 15) == 0) {
      int word = lane >> 4;
      size_t base = ((size_t)slice*3*Hh + row)*MROWSTRIDE + word;
      masks[base]                    = m1;
      masks[base + Hh*MROWSTRIDE]    = m2;
      masks[base + 2*Hh*MROWSTRIDE]  = m3;
    }
  }
  __shared__ unsigned int sb;
  if (threadIdx.x == 0) sb = 0u;
  __syncthreads();
  if (lbits) atomicOr(&sb, lbits);
  __syncthreads();
  if (threadIdx.x == 0 && sb) atomicOr(&flags[slice], sb);
}

// nearest set bit distance from column j in a 192-bit row mask; 1<<20 if empty
__device__ __forceinline__ int nearest_bit_dist(u64 m0, u64 m1, u64 m2, int j) {
  int dr = 1<<20, dl = 1<<20;
  u64 r0, r1, r2;
  if (j >= 128)      { r0 = 0;  r1 = 0;  r2 = m2 & (~0ull << (j-128)); }
  else if (j >= 64)  { r0 = 0;  r1 = m1 & (~0ull << (j-64)); r2 = m2; }
  else               { r0 = m0 & (~0ull << j); r1 = m1; r2 = m2; }
  if      (r0) dr = (__ffsll((unsigned long long)r0) - 1) - j;
  else if (r1) dr = (__ffsll((unsigned long long)r1) + 63) - j;
  else if (r2) dr = (__ffsll((unsigned long long)r2) + 127) - j;
  u64 l0, l1, l2;
  if (j < 64)        { l0 = (j==63) ? m0 : (m0 & ((1ull<<(j+1))-1)); l1 = 0; l2 = 0; }
  else if (j < 128)  { l0 = m0; l1 = (j==127) ? m1 : (m1 & ((1ull<<(j-63))-1)); l2 = 0; }
  else               { l0 = m0; l1 = m1; l2 = (j==191) ? m2 : (m2 & ((1ull<<(j-127))-1)); }
  if      (l2) dl = j - (191 - __clzll((long long)l2));
  else if (l1) dl = j - (127 - __clzll((long long)l1));
  else if (l0) dl = j - (63  - __clzll((long long)l0));
  return dl < dr ? dl : dr;
}

// wave-aggregated worklist push: 1 LDS atomic per wave instead of per lane
__device__ __forceinline__ void push_items(unsigned short* list,
    unsigned int* cnt, bool want, unsigned val) {
  u64 mask = __ballot(want);
  if (mask == 0) return;
  int lane = threadIdx.x & 63;
  int total = __popcll(mask);
  int leader = __ffsll((long long)mask) - 1;
  unsigned b = 0;
  if (lane == leader) b = atomicAdd(cnt, (unsigned)total);
  b = __shfl(b, leader);
  if (want) {
    int off = __popcll(mask & ((1ull << lane) - 1));
    list[b + off] = (unsigned short)val;
  }
}

// ---------------- Kernel B: worklist-compacted exact EDT ---------------------
// grid: NSLICE*18 blocks of 256; 2048 px per block (small LDS -> high occupancy).
__global__ __launch_bounds__(256) void edt_kernel(const unsigned char* __restrict__ tp,
    const u64* __restrict__ masks, const unsigned int* __restrict__ flags,
    float* __restrict__ wmap, unsigned int* __restrict__ mnb,
    unsigned int* __restrict__ mxb) {
  __shared__ __align__(16) float wacc[2048];
  __shared__ unsigned short list[4096];
  __shared__ unsigned int cnt;
  __shared__ float smn[4], smx[4];
  int part  = blockIdx.x % 18;
  int slice = blockIdx.x / 18;
  unsigned int fl = flags[slice];
  bool empty = ((fl & 7u) == 0u);
  if (threadIdx.x == 0) cnt = 0u;
  __syncthreads();

  // phase 1: worklist build + wacc init (8 px per thread)
  for (int it = 0; it < 2; ++it) {
    int lbase = it*1024 + threadIdx.x*4;
    unsigned pk = *(const unsigned*)(tp + (size_t)slice*HW + part*2048 + lbase);
    #pragma unroll
    for (int k = 0; k < 4; ++k) {
      int byte = (pk >> (8*k)) & 0xff;
      int tv = byte & 15, pv = byte >> 4;
      wacc[lbase+k] = (empty && pv != 0) ? 10.0f : 0.0f;
      bool diff = (tv != pv);
      bool w1 = diff && (tv >= 1) && ((fl >> (tv-1)) & 1u);
      bool w2 = diff && (pv >= 1) && ((fl >> (pv-1)) & 1u);
      push_items(list, &cnt, w1, (unsigned)(lbase+k) | ((unsigned)tv << 12));
      push_items(list, &cnt, w2, (unsigned)(lbase+k) | ((unsigned)pv << 12));
    }
  }
  __syncthreads();

  // phase 2: uniform ring searches
  unsigned n = cnt;
  const u64* msl = masks + (size_t)slice*3*Hh*MROWSTRIDE;
  for (unsigned kk = threadIdx.x; kk < n; kk += 256) {
    unsigned item = list[kk];
    int lidx = item & 2047;
    int c = item >> 12;
    int idx = part*2048 + lidx;
    int i = idx / Ww, j = idx - i*Ww;
    const u64* M = msl + (size_t)(c-1)*Hh*MROWSTRIDE;
    int best = 1 << 30;
    for (int dr = 0; dr < Hh; ++dr) {
      int dr2 = dr*dr;
      if (dr2 >= best) break;
      int up = i - dr;
      if (up >= 0) {
        const u64* R = M + up*MROWSTRIDE;
        int dc = nearest_bit_dist(R[0], R[1], R[2], j);
        if (dc < (1<<20)) { int cand = dr2 + dc*dc; if (cand < best) best = cand; }
      }
      int dn = i + dr;
      if (dr && dn < Hh) {
        const u64* R = M + dn*MROWSTRIDE;
        int dc = nearest_bit_dist(R[0], R[1], R[2], j);
        if (dc < (1<<20)) { int cand = dr2 + dc*dc; if (cand < best) best = cand; }
      }
    }
    float dist = (best == (1 << 30)) ? 1.0e6f : sqrtf((float)best);
    atomicAdd(&wacc[lidx], dist);
  }
  __syncthreads();

  // phase 3: writeback + min/max
  float lmn = 1.0e30f, lmx = 0.0f;
  for (int it = 0; it < 2; ++it) {
    int lbase = it*1024 + threadIdx.x*4;
    float4 wv = *(const float4*)&wacc[lbase];
    lmn = fminf(lmn, fminf(fminf(wv.x, wv.y), fminf(wv.z, wv.w)));
    lmx = fmaxf(lmx, fmaxf(fmaxf(wv.x, wv.y), fmaxf(wv.z, wv.w)));
    *(float4*)(wmap + (size_t)slice*HW + part*2048 + lbase) = wv;
  }
  for (int off = 32; off; off >>= 1) {
    lmn = fminf(lmn, __shfl_xor(lmn, off));
    lmx = fmaxf(lmx, __shfl_xor(lmx, off));
  }
  int wid = threadIdx.x >> 6;
  if ((threadIdx.x & 63) == 0) { smn[wid] = lmn; smx[wid] = lmx; }
  __syncthreads();
  if (threadIdx.x == 0) {
    lmn = fminf(fminf(smn[0], smn[1]), fminf(smn[2], smn[3]));
    lmx = fmaxf(fmaxf(smx[0], smx[1]), fmaxf(smx[2], smx[3]));
    atomicMin(&mnb[slice], __float_as_uint(lmn));
    atomicMax(&mxb[slice], __float_as_uint(lmx));
  }
}

// ---------------- Kernel C: sum focal * exp(normalized wmap) -----------------
__global__ __launch_bounds__(256) void loss_kernel(const float* __restrict__ focal,
    const float* __restrict__ wmap, const unsigned int* __restrict__ mnb,
    const unsigned int* __restrict__ mxb, float* __restrict__ out) {
  int part  = blockIdx.x % 9;
  int slice = blockIdx.x / 9;
  float mn = __uint_as_float(mnb[slice]);
  float mx = __uint_as_float(mxb[slice]);
  float inv = 1.0f/(mx - mn + 1e-6f);
  float acc = 0.0f;
  for (int it = 0; it < 4; ++it) {
    int idx = part*4096 + it*1024 + threadIdx.x*4;
    float4 f = *(const float4*)(focal + (size_t)slice*HW + idx);
    float4 w = *(const float4*)(wmap + (size_t)slice*HW + idx);
    acc += f.x * expf((w.x-mn)*inv);
    acc += f.y * expf((w.y-mn)*inv);
    acc += f.z * expf((w.z-mn)*inv);
    acc += f.w * expf((w.w-mn)*inv);
  }
  for (int off = 32; off; off >>= 1) acc += __shfl_xor(acc, off);
  __shared__ float sa[4];
  int wid = threadIdx.x >> 6;
  if ((threadIdx.x & 63) == 0) sa[wid] = acc;
  __syncthreads();
  if (threadIdx.x == 0) atomicAdd(out, sa[0]+sa[1]+sa[2]+sa[3]);
}

extern "C" void kernel_launch(void* const* d_in, const int* in_sizes, int n_in,
                              void* d_out, int out_size, void* d_ws, size_t ws_size,
                              hipStream_t stream) {
  const float* inp = (const float*)d_in[0];
  const int*   tgt = (const int*)d_in[1];
  char* ws = (char*)d_ws;
  unsigned char* tp    = (unsigned char*)ws;                // NVOX bytes
  float*         focal = (float*)(ws + NVOX);               // 4*NVOX
  float*         wmap  = (float*)(ws + 5*NVOX);             // 4*NVOX
  u64*           masks = (u64*)(ws + 9*NVOX);               // MASKU64*8
  unsigned int*  flags = (unsigned int*)(ws + 9*NVOX + MASKU64*8);
  unsigned int*  mxb   = flags + NSLICE;
  unsigned int*  mnb   = mxb + NSLICE;

  hipMemsetAsync(flags, 0, NSLICE*2*sizeof(unsigned int), stream); // flags + mxb
  hipMemsetAsync(mnb, 0xFF, NSLICE*sizeof(unsigned int), stream);  // mnb = huge
  hipMemsetAsync(d_out, 0, sizeof(float), stream);

  prep_kernel<<<NSLICE*8, 256, 0, stream>>>(inp, tgt, tp, focal, masks, flags);
  edt_kernel<<<NSLICE*18, 256, 0, stream>>>(tp, masks, flags, wmap, mnb, mxb);
  loss_kernel<<<NSLICE*9, 256, 0, stream>>>(focal, wmap, mnb, mxb, (float*)d_out);
}